// Round 14
// baseline (118.677 us; speedup 1.0000x reference)
//
#include <hip/hip_runtime.h>
#include <math.h>

#define NA    180
#define PC    262           // row stride in texels (cols 0..260 valid, 261 = pad)
#define PR    266           // rows: pv = v+3, v = -3..262
#define OUTN  (8 * NA * 256)
#define NCH   12            // k-chunks per ray (grid parallelism, no LDS)

typedef _Float16 h2  __attribute__((ext_vector_type(2)));
typedef _Float16 h8  __attribute__((ext_vector_type(8)));
typedef __fp16   hf2 __attribute__((ext_vector_type(2)));

__device__ __forceinline__ h2 pkrtz(float a, float b) {
    hf2 t = __builtin_amdgcn_cvt_pkrtz(a, b);
    return __builtin_bit_cast(h2, t);
}
__device__ __forceinline__ float fdot2f(h2 a, h2 b, float c) {
#if __has_builtin(__builtin_amdgcn_fdot2)
    return __builtin_amdgcn_fdot2(__builtin_bit_cast(hf2, a),
                                  __builtin_bit_cast(hf2, b), c, false);
#else
    return c + (float)a.x * (float)b.x + (float)a.y * (float)b.y;
#endif
}
__device__ __forceinline__ float imc(const float* im, int y, int x) {
    return ((unsigned)y < 256u && (unsigned)x < 256u) ? im[(y << 8) + x] : 0.0f;
}

// ALL-8-batch packed texels (8 x f16 per 16 B uint4), identical
// [266 rows (pv=v+3)][262 cols (u+2, col 261 = zero pad)] geometry.
// Total 2 x 1.1 MB -> fully L2-resident per XCD (4 MB). Radon samples
// straight from L2/L1 — no LDS staging at all.
//  P0 [pv][j] : f16 im_b(v,u) for b=0..7,  v=pv-3, u=j-2   (Y-mode)
//  P1t[pv][j] : f16 im_b(u,v) for b=0..7,  v=pv-3, u=j-2   (X-mode)
__global__ __launch_bounds__(256) void prep_kernel(
    const float* __restrict__ img, uint4* __restrict__ P0,
    uint4* __restrict__ P1, float* __restrict__ out, float* __restrict__ tab)
{
    const int tid = threadIdx.x;
    const int row = blockIdx.x;            // 0..PR-1
    const int mb  = blockIdx.y;            // 0: P0 ; 1: P1t

    if (mb == 0) {                         // zero the atomic output
        for (int i = row * 256 + tid; i < OUTN; i += PR * 256) out[i] = 0.0f;
    }
    if (mb == 1 && row == 0 && tid < NA) { // angle table
        const float theta = (float)tid * ((float)M_PI / (float)NA);
        tab[tid]      = cosf(theta);
        tab[tid + NA] = sinf(theta);
    }

    const int v = row - 3;
    uint4* dst = (mb == 0 ? P0 : P1) + (size_t)row * PC;
    for (int j = tid; j < PC; j += 256) {
        const int u = j - 2;
        h8 t = {};
        if (j < 261) {
            if (mb == 0) {
                #pragma unroll
                for (int b = 0; b < 8; ++b)
                    t[b] = (_Float16)imc(img + ((size_t)b << 16), v, u);
            } else {
                #pragma unroll
                for (int b = 0; b < 8; ++b)
                    t[b] = (_Float16)imc(img + ((size_t)b << 16), u, v);
            }
        }
        dst[j] = __builtin_bit_cast(uint4, t);
    }
}

// One sample, all 8 batches, straight from global (L1/L2-resident):
// 4 x global_load_dwordx4 (corners), v-lerp packed f16, u-lerp + span
// mask folded into one h2 weight -> 8 v_dot2 accumulates.
#define SAMPLE8G(JV, UV, VPV, ACC)                                            \
    {                                                                         \
        const float ucl = fminf(fmaxf((UV), -1.5f), 257.5f);                  \
        const float uf = floorf(ucl);                                         \
        const float wu = ucl - uf;                                            \
        float vf = floorf(VPV);                                               \
        vf = fminf(fmaxf(vf, -2.0f), 258.0f);                                 \
        const float wv = (VPV) - vf;                                          \
        const int idx = (int)fmaf(vf, (float)PC, uf) + (3 * PC + 2);          \
        const h8 ra0 = __builtin_bit_cast(h8, P[idx]);                        \
        const h8 ra1 = __builtin_bit_cast(h8, P[idx + 1]);                    \
        const h8 rb0 = __builtin_bit_cast(h8, P[idx + PC]);                   \
        const h8 rb1 = __builtin_bit_cast(h8, P[idx + PC + 1]);               \
        const h2 wv2 = pkrtz(wv, wv);                                         \
        const h8 wv8 = __builtin_shufflevector(wv2, wv2, 0,1,0,1,0,1,0,1);    \
        const h8 v0 = (rb0 - ra0) * wv8 + ra0;                                \
        const h8 v1 = (rb1 - ra1) * wv8 + ra1;                                \
        h2 wu2 = pkrtz(1.0f - wu, wu);                                        \
        wu2 = ((unsigned)(JV) < uspan) ? wu2 : hz;                            \
        ACC[0] = fdot2f(__builtin_shufflevector(v0, v1, 0,  8), wu2, ACC[0]); \
        ACC[1] = fdot2f(__builtin_shufflevector(v0, v1, 1,  9), wu2, ACC[1]); \
        ACC[2] = fdot2f(__builtin_shufflevector(v0, v1, 2, 10), wu2, ACC[2]); \
        ACC[3] = fdot2f(__builtin_shufflevector(v0, v1, 3, 11), wu2, ACC[3]); \
        ACC[4] = fdot2f(__builtin_shufflevector(v0, v1, 4, 12), wu2, ACC[4]); \
        ACC[5] = fdot2f(__builtin_shufflevector(v0, v1, 5, 13), wu2, ACC[5]); \
        ACC[6] = fdot2f(__builtin_shufflevector(v0, v1, 6, 14), wu2, ACC[6]); \
        ACC[7] = fdot2f(__builtin_shufflevector(v0, v1, 7, 15), wu2, ACC[7]); \
    }

template<bool MODEX>
__device__ __forceinline__ void radon_ray(
    const uint4* __restrict__ P,   // P0 (Y-mode) / P1t (X-mode)
    float* __restrict__ out, const float* __restrict__ tab,
    int tid, int a, int chunk)
{
    const float c = tab[a];            // uniform -> scalar load
    const float s = tab[a + NA];
    const float detf = (float)tid - 127.5f;

    const float xc = 127.5f + detf * c + 127.5f * s;   // x at k=0
    const float yc = 127.5f + detf * s - 127.5f * c;   // y at k=0

    const float ucst = MODEX ? yc : xc;
    const float vcst = MODEX ? xc : yc;
    const float du   = MODEX ? c  : -s;
    const float dv   = MODEX ? -s : c;

    // per-lane in-image k-window: samples with v or u outside (-1, 256)
    // read only zero border texels -> dropping them is exact.
    const float iv = 1.0f / dv;
    const float va = (-1.0f - vcst) * iv, vb = (256.0f - vcst) * iv;
    const float iu = 1.0f / du;
    const float ua = (-1.0f - ucst) * iu, ub = (256.0f - ucst) * iu;
    float lo = fmaxf(fminf(va, vb), fminf(ua, ub));
    float hi = fminf(fmaxf(va, vb), fmaxf(ua, ub));
    lo = fminf(fmaxf(lo, 0.0f), 512.0f);     // clamp + saturate inf/NaN
    hi = fminf(fmaxf(hi, -1.0f), 256.0f);
    const int kmin = (int)ceilf(lo);
    const int kend = min(256, (int)floorf(hi) + 1);
    const int len  = max(0, kend - kmin);

    // even per-lane split into NCH chunks (integer partition -> exact)
    const int clen = (len + (NCH - 1)) / NCH;
    const int k0   = kmin + chunk * clen;
    const int span = min(clen, kend - k0);       // may be <= 0

    // wave-max span -> uniform loop bound
    int m = span;
    m = max(m, __shfl_xor(m, 1));
    m = max(m, __shfl_xor(m, 2));
    m = max(m, __shfl_xor(m, 4));
    m = max(m, __shfl_xor(m, 8));
    m = max(m, __shfl_xor(m, 16));
    m = max(m, __shfl_xor(m, 32));
    const int mspan = __builtin_amdgcn_readfirstlane(m);
    if (mspan <= 0) return;
    const unsigned uspan = (unsigned)max(span, 0);
    const h2 hz = {};

    float u  = fmaf((float)k0, du, ucst);
    float vp = fmaf((float)k0, dv, vcst);        // absolute v
    const float du2 = du + du, dv2 = dv + dv;
    const float du3 = du2 + du, dv3 = dv2 + dv;
    const float du4 = du2 + du2, dv4 = dv2 + dv2;

    float accA[8] = {}, accB[8] = {}, accC[8] = {}, accD[8] = {};

    int j = 0;
    for (; j + 3 < mspan; j += 4) {              // 4 indep chains
        SAMPLE8G(j,     u,       vp,       accA);
        SAMPLE8G(j + 1, u + du,  vp + dv,  accB);
        SAMPLE8G(j + 2, u + du2, vp + dv2, accC);
        SAMPLE8G(j + 3, u + du3, vp + dv3, accD);
        u += du4; vp += dv4;
    }
    for (; j + 1 < mspan; j += 2) {
        SAMPLE8G(j,     u,      vp,      accA);
        SAMPLE8G(j + 1, u + du, vp + dv, accB);
        u += du2; vp += dv2;
    }
    if (j < mspan) SAMPLE8G(j, u, vp, accA);

    if (span > 0) {
        float* o = &out[(a << 8) + tid];
        #pragma unroll
        for (int b = 0; b < 8; ++b)
            atomicAdd(o + b * (NA << 8),
                      (accA[b] + accC[b]) + (accB[b] + accD[b]));
    }
}

// grid = (NA angles, NCH k-chunks); block = 256 detectors. No LDS.
__global__ __launch_bounds__(256, 4) void radon_kernel(
    const uint4* __restrict__ P0, const uint4* __restrict__ P1,
    float* __restrict__ out, const float* __restrict__ tab)
{
    const int a     = blockIdx.x;                // 0..NA-1
    const int chunk = blockIdx.y;                // 0..NCH-1
    if (a >= 46 && a < 135)
        radon_ray<true >(P1, out, tab, threadIdx.x, a, chunk);
    else
        radon_ray<false>(P0, out, tab, threadIdx.x, a, chunk);
}

extern "C" void kernel_launch(void* const* d_in, const int* in_sizes, int n_in,
                              void* d_out, int out_size, void* d_ws, size_t ws_size,
                              hipStream_t stream) {
    const float* img = (const float*)d_in[0];
    float* out = (float*)d_out;

    uint4* P0 = (uint4*)d_ws;                       // 266*262*16 B
    uint4* P1 = P0 + (size_t)PR * PC;               // 266*262*16 B
    float* tab = (float*)(P1 + (size_t)PR * PC);    // 360 floats

    prep_kernel<<<dim3(PR, 2), 256, 0, stream>>>(img, P0, P1, out, tab);
    radon_kernel<<<dim3(NA, NCH), 256, 0, stream>>>(P0, P1, out, tab);
}

// Round 15
// 101.065 us; speedup vs baseline: 1.1743x; 1.1743x over previous
//
#include <hip/hip_runtime.h>
#include <math.h>

#define NA    180
#define HB    9             // band height in v
#define KB    29            // bands cover v in [-2, 259)
#define PC    262           // row stride in texels (cols 0..260 valid, 261 = pad)
#define PR    264           // rows: pv = v+3, v = -3..260
#define TROWS 12            // tile v-rows: v = lo-1 .. lo+10
#define TSZ   (PC * TROWS)  // 3144 uint2 = 25,152 B -> 6 blocks/CU
#define TSZ4  (TSZ / 2)     // staged as uint4
#define OUTN  (8 * NA * 256)
#define APG   4             // angles per block (fine-grained for tail balance)
#define NG    23            // ceil(91/APG) groups per mode

typedef _Float16 h2  __attribute__((ext_vector_type(2)));
typedef _Float16 h4  __attribute__((ext_vector_type(4)));
typedef __fp16   hf2 __attribute__((ext_vector_type(2)));

__device__ __forceinline__ h2 pkrtz(float a, float b) {
    hf2 t = __builtin_amdgcn_cvt_pkrtz(a, b);
    return __builtin_bit_cast(h2, t);
}
__device__ __forceinline__ float fdot2f(h2 a, h2 b, float c) {
#if __has_builtin(__builtin_amdgcn_fdot2)
    return __builtin_amdgcn_fdot2(__builtin_bit_cast(hf2, a),
                                  __builtin_bit_cast(hf2, b), c, false);
#else
    return c + (float)a.x * (float)b.x + (float)a.y * (float)b.y;
#endif
}
__device__ __forceinline__ float imc(const float* im, int y, int x) {
    return ((unsigned)y < 256u && (unsigned)x < 256u) ? im[(y << 8) + x] : 0.0f;
}

// Non-duplicated batch-packed texels (4 batches per 8 B uint2), identical
// [264 rows (pv=v+3)][262 cols (u+2, col 261 = zero pad)] geometry for both:
//  P0 [bg][pv][j] : 4 x f16 im_b(v,u),  v=pv-3, u=j-2   (Y-mode)
//  P1t[bg][pv][j] : 4 x f16 im_b(u,v),  v=pv-3, u=j-2   (X-mode, transposed)
__global__ __launch_bounds__(256) void prep_kernel(
    const float* __restrict__ img, uint2* __restrict__ P0,
    uint2* __restrict__ P1, float* __restrict__ out, float* __restrict__ tab)
{
    const int tid = threadIdx.x;
    const int row = blockIdx.x;            // 0..PR-1
    const int mb  = blockIdx.y;            // 0,1: P0 bg ; 2,3: P1t bg

    if (mb == 0) {                         // zero the atomic output
        for (int i = row * 256 + tid; i < OUTN; i += PR * 256) out[i] = 0.0f;
    }
    if (mb == 1 && row == 0 && tid < NA) { // angle table
        const float theta = (float)tid * ((float)M_PI / (float)NA);
        tab[tid]      = cosf(theta);
        tab[tid + NA] = sinf(theta);
    }

    const int bg = mb & 1;
    const float* im0 = img + ((size_t)(bg * 4) << 16);
    const int v = row - 3;

    if (mb < 2) {
        uint2* dst = P0 + (size_t)(bg * PR + row) * PC;
        for (int j = tid; j < PC; j += 256) {
            const int u = j - 2;
            h4 t = {};
            if (j < 261) {
                t[0] = (_Float16)imc(im0,             v, u);
                t[1] = (_Float16)imc(im0 + (1 << 16), v, u);
                t[2] = (_Float16)imc(im0 + (2 << 16), v, u);
                t[3] = (_Float16)imc(im0 + (3 << 16), v, u);
            }
            dst[j] = __builtin_bit_cast(uint2, t);
        }
    } else {
        uint2* dst = P1 + (size_t)(bg * PR + row) * PC;
        for (int j = tid; j < PC; j += 256) {
            const int u = j - 2;
            h4 t = {};
            if (j < 261) {
                t[0] = (_Float16)imc(im0,             u, v);
                t[1] = (_Float16)imc(im0 + (1 << 16), u, v);
                t[2] = (_Float16)imc(im0 + (2 << 16), u, v);
                t[3] = (_Float16)imc(im0 + (3 << 16), u, v);
            }
            dst[j] = __builtin_bit_cast(uint2, t);
        }
    }
}

// One sample: read 4 texels (rows v,v+1 x cols u,u+1), v-lerp in packed f16,
// u-lerp via fdot2 into f32 accs.
#define SAMPLE(JV, UV, VPV, A0, A1, A2, A3)                                   \
    {                                                                         \
        const float ucl = fminf(fmaxf((UV), -1.5f), 257.5f);                  \
        const float uf = floorf(ucl);                                         \
        const float wu = ucl - uf;                                            \
        const float vf = floorf(VPV);                                         \
        const float wv = (VPV) - vf;                                          \
        const float vfc = fminf(fmaxf(vf, -1.0f), 9.0f);                      \
        const int idx = (int)fmaf(vfc, (float)PC, uf) + (PC + 2);             \
        const h4 r00 = __builtin_bit_cast(h4, s_tile[idx]);                   \
        const h4 r01 = __builtin_bit_cast(h4, s_tile[idx + 1]);               \
        const h4 r10 = __builtin_bit_cast(h4, s_tile[idx + PC]);              \
        const h4 r11 = __builtin_bit_cast(h4, s_tile[idx + PC + 1]);          \
        const h2 wv2 = pkrtz(wv, wv);                                         \
        const h4 wv4 = __builtin_shufflevector(wv2, wv2, 0, 1, 0, 1);         \
        const h4 V0 = (r10 - r00) * wv4 + r00;                                \
        const h4 V1 = (r11 - r01) * wv4 + r01;                                \
        h2 wu2 = pkrtz(1.0f - wu, wu);                                        \
        wu2 = ((unsigned)(JV) < span) ? wu2 : hz;                             \
        A0 = fdot2f(__builtin_shufflevector(V0, V1, 0, 4), wu2, A0);          \
        A1 = fdot2f(__builtin_shufflevector(V0, V1, 1, 5), wu2, A1);          \
        A2 = fdot2f(__builtin_shufflevector(V0, V1, 2, 6), wu2, A2);          \
        A3 = fdot2f(__builtin_shufflevector(V0, V1, 3, 7), wu2, A3);          \
    }

template<bool MODEX>
__device__ __forceinline__ void radon_body(
    const uint2* __restrict__ Pbase,   // batch-group base of P0 (Y) / P1t (X)
    float* __restrict__ out, const float* __restrict__ tab,
    uint2* s_tile, int tid, int b0, int p, int gi)
{
    const int lo = -2 + p * HB;

    // ---- stage band tile: rows pv = lo+2 .. lo+13 (v = lo-1..lo+10)
    {
        const uint4* src = (const uint4*)(Pbase + (size_t)(lo + 2) * PC);
        uint4* dst = (uint4*)s_tile;
        for (int i = tid; i < TSZ4; i += 256) dst[i] = src[i];
    }
    __syncthreads();

    const float detf = (float)tid - 127.5f;
    const float lof = (float)lo;
    const h2 hz = {};

    for (int g = 0; g < APG; ++g) {
        const int ai = gi * APG + g;
        int a;
        if (MODEX) { if (ai >= 89) break; a = 46 + ai; }   // 46..134
        else       { if (ai >= 91) break; a = (ai <= 45) ? ai : 89 + ai; }

        const float c = tab[a];            // uniform -> scalar load
        const float s = tab[a + NA];

        const float xc = 127.5f + detf * c + 127.5f * s;   // x at k=0
        const float yc = 127.5f + detf * s - 127.5f * c;   // y at k=0

        const float ucst = MODEX ? yc : xc;
        const float vcst = MODEX ? xc : yc;
        const float du   = MODEX ? c  : -s;
        const float dv   = MODEX ? -s : c;

        // band-crossing k-window; identical float exprs on shared boundaries
        // of adjacent bands -> exact partition of k-space (no dup/miss)
        const float inv = 1.0f / dv;
        const float f1 = (lof - vcst) * inv;
        const float f2 = (lof + (float)HB - vcst) * inv;
        const float fmn = fminf(f1, f2);
        const float fmx = fmaxf(f1, f2);
        int kmin, kend;
        if (dv > 0.0f) { kmin = (int)ceilf(fmn);      kend = (int)ceilf(fmx); }
        else           { kmin = (int)floorf(fmn) + 1; kend = (int)floorf(fmx) + 1; }

        const int len = kend - kmin;
        const int jlo = max(0, -kmin);
        const int jhi = min(len, 256 - kmin);
        const int spani = max(0, jhi - jlo);
        if (!__any(spani > 0)) continue;
        const unsigned span = (unsigned)spani;

        const int kstart = kmin + jlo;
        const int Lmax = (int)((float)HB * fabsf(inv)) + 2;  // angle-uniform

        float u  = fmaf((float)kstart, du, ucst);
        float vp = fmaf((float)kstart, dv, vcst - lof);      // v relative to lo
        const float du2 = du + du, dv2 = dv + dv;
        const float du3 = du2 + du, dv3 = dv2 + dv;
        const float du4 = du2 + du2, dv4 = dv2 + dv2;

        float a0 = 0.f, a1 = 0.f, a2 = 0.f, a3 = 0.f;       // 4 indep chains
        float e0 = 0.f, e1 = 0.f, e2 = 0.f, e3 = 0.f;
        float c0 = 0.f, c1 = 0.f, c2 = 0.f, c3 = 0.f;
        float d0 = 0.f, d1 = 0.f, d2 = 0.f, d3 = 0.f;

        int j = 0;
        for (; j + 3 < Lmax; j += 4) {
            SAMPLE(j,     u,        vp,        a0, a1, a2, a3);
            SAMPLE(j + 1, u + du,   vp + dv,   e0, e1, e2, e3);
            SAMPLE(j + 2, u + du2,  vp + dv2,  c0, c1, c2, c3);
            SAMPLE(j + 3, u + du3,  vp + dv3,  d0, d1, d2, d3);
            u += du4; vp += dv4;
        }
        for (; j + 1 < Lmax; j += 2) {
            SAMPLE(j,     u,      vp,      a0, a1, a2, a3);
            SAMPLE(j + 1, u + du, vp + dv, e0, e1, e2, e3);
            u += du2; vp += dv2;
        }
        if (j < Lmax) SAMPLE(j, u, vp, a0, a1, a2, a3);

        if (spani > 0) {
            float* o = &out[((b0 * NA + a) << 8) + tid];
            atomicAdd(o,                 (a0 + c0) + (e0 + d0));
            atomicAdd(o + (NA << 8),     (a1 + c1) + (e1 + d1));
            atomicAdd(o + 2 * (NA << 8), (a2 + c2) + (e2 + d2));
            atomicAdd(o + 3 * (NA << 8), (a3 + c3) + (e3 + d3));
        }
    }
}

// grid = (2 batch-groups, KB bands, 2*NG angle-groups)
__global__ __launch_bounds__(256, 6) void radon_kernel(
    const uint2* __restrict__ P0, const uint2* __restrict__ P1,
    float* __restrict__ out, const float* __restrict__ tab)
{
    __shared__ uint2 s_tile[TSZ];                  // 25,152 B -> 6 blocks/CU
    const int tid = threadIdx.x;
    const int bg  = blockIdx.x;
    const int p   = blockIdx.y;
    const int gid = blockIdx.z;                    // 0..2*NG-1
    const int b0  = bg * 4;
    if (gid < NG)
        radon_body<false>(P0 + (size_t)bg * PR * PC, out, tab, s_tile, tid, b0, p, gid);
    else
        radon_body<true>(P1 + (size_t)bg * PR * PC, out, tab, s_tile, tid, b0, p, gid - NG);
}

extern "C" void kernel_launch(void* const* d_in, const int* in_sizes, int n_in,
                              void* d_out, int out_size, void* d_ws, size_t ws_size,
                              hipStream_t stream) {
    const float* img = (const float*)d_in[0];
    float* out = (float*)d_out;

    uint2* P0 = (uint2*)d_ws;                       // 2*264*262*8 B
    uint2* P1 = P0 + (size_t)2 * PR * PC;           // 2*264*262*8 B
    float* tab = (float*)(P1 + (size_t)2 * PR * PC);    // 360 floats

    prep_kernel<<<dim3(PR, 4), 256, 0, stream>>>(img, P0, P1, out, tab);
    radon_kernel<<<dim3(2, KB, 2 * NG), 256, 0, stream>>>(P0, P1, out, tab);
}